// Round 8
// baseline (374.600 us; speedup 1.0000x reference)
//
#include <hip/hip_runtime.h>
#include <hip/hip_bf16.h>
#include <stdint.h>

// Problem constants
#define NATOMS 32768
#define DDIM   1024
#define HDIM   1024
#define ENUM   4
#define MCAP   (NATOMS + ENUM * 128)   // 33280 = 260 * 128 (worst-case padded M)
#define MTILES 260

typedef unsigned short u16;
typedef unsigned char  u8;
typedef __attribute__((ext_vector_type(8)))  int   i32x8;
typedef __attribute__((ext_vector_type(16))) float f32x16;

// ---- workspace layout (bytes) ----
static const size_t XP_OFF   = 0;
static const size_t H1_OFF   = XP_OFF  + (size_t)MCAP * 1024;
static const size_t W1T_OFF  = H1_OFF  + (size_t)MCAP * 1024;
static const size_t W2T_OFF  = W1T_OFF + (size_t)ENUM * 1024 * 1024;
static const size_t PERM_OFF = W2T_OFF + (size_t)ENUM * 1024 * 1024;
static const size_t META_OFF = PERM_OFF + (size_t)MCAP * 4;
// meta ints: count[e] at e*16; cursor[e] at 64+e*16; offs[0..3] at 128..131;
// Mpad at 132; per-block count partials at 256 + b*4 + e  (b in [0,128))

__device__ __forceinline__ u8 f2fp8(float x) {
    int w = __builtin_amdgcn_cvt_pk_fp8_f32(x, x, 0, false);
    return (u8)(w & 0xFF);
}

// ------- count atoms per expert: per-block partials, no pre-zeroed meta -------
__global__ void k_count(const int* __restrict__ sym, int* __restrict__ meta) {
    __shared__ int cnt[4];
    int t = threadIdx.x;
    if (t < 4) cnt[t] = 0;
    __syncthreads();
    int n = blockIdx.x * 256 + t;
    int lane = t & 63;
    int e = sym[n];
#pragma unroll
    for (int j = 0; j < ENUM; ++j) {
        unsigned long long mask = __ballot(e == j);
        if (mask) {
            int leader = __ffsll((long long)mask) - 1;
            if (lane == leader) atomicAdd(&cnt[j], __popcll(mask));
        }
    }
    __syncthreads();
    if (t < 4) meta[256 + blockIdx.x * 4 + t] = cnt[t];
}

// -- sum partials; write counts/cursors/offs/Mpad; out = constant energy term --
__global__ void k_offsets(int* __restrict__ meta, const float* __restrict__ slope,
                          const float* __restrict__ b3, const float* __restrict__ inter,
                          float* __restrict__ out) {
    __shared__ int tot[4];
    int t = threadIdx.x;
    if (t < 4) {
        int s = 0;
#pragma unroll 8
        for (int b = 0; b < 128; ++b) s += meta[256 + b * 4 + t];
        tot[t] = s;
    }
    __syncthreads();
    if (t == 0) {
        int off = 0;
        float c = 0.f;
        for (int e = 0; e < 4; ++e) {
            int cnt = tot[e];
            meta[e * 16]     = cnt;   // total count
            meta[128 + e]    = off;   // segment start
            meta[64 + e*16]  = off;   // scatter cursor
            c += (float)cnt * (slope[e] * b3[e] + inter[e]);
            off += (cnt + 127) & ~127;
        }
        meta[132] = off;              // Mpad
        out[0] = c;                   // per-atom constant terms, summed
    }
}

// ---------------- scatter atom ids (wave-aggregated: 4 atomics/wave) ----------------
__global__ void k_scatter(const int* __restrict__ sym, int* __restrict__ meta,
                          int* __restrict__ perm) {
    int n = blockIdx.x * 256 + threadIdx.x;
    int lane = threadIdx.x & 63;
    int e = sym[n];
#pragma unroll
    for (int j = 0; j < ENUM; ++j) {
        unsigned long long mask = __ballot(e == j);
        if (mask) {
            int leader = __ffsll((long long)mask) - 1;
            int base = 0;
            if (lane == leader)
                base = atomicAdd(&meta[64 + j * 16], __popcll(mask));
            base = __shfl(base, leader, 64);
            if (e == j) {
                int rank = __popcll(mask & ((1ull << lane) - 1ull));
                perm[base + rank] = n;
            }
        }
    }
}

// -------- features fp32 -> permuted fp8 (pad slots -> zeros, via offs/count) --------
__global__ void k_convx(const float* __restrict__ F, const int* __restrict__ perm,
                        const int* __restrict__ meta, u8* __restrict__ Xp) {
    int g = blockIdx.x * 256 + threadIdx.x;    // chunk of 8 elements
    int slot = g >> 7, c = g & 127;
    const int* offs = meta + 128;
    int e = (slot >= offs[1]) + (slot >= offs[2]) + (slot >= offs[3]);
    bool valid = slot < offs[e] + meta[e * 16];
    uint2 v;
    if (!valid) {
        v.x = 0u; v.y = 0u;
    } else {
        int src = perm[slot];
        const float* fp = F + (size_t)src * 1024 + c * 8;
        int w0 = 0, w1 = 0;
        w0 = __builtin_amdgcn_cvt_pk_fp8_f32(fp[0], fp[1], w0, false);
        w0 = __builtin_amdgcn_cvt_pk_fp8_f32(fp[2], fp[3], w0, true);
        w1 = __builtin_amdgcn_cvt_pk_fp8_f32(fp[4], fp[5], w1, false);
        w1 = __builtin_amdgcn_cvt_pk_fp8_f32(fp[6], fp[7], w1, true);
        v.x = (unsigned)w0; v.y = (unsigned)w1;
    }
    *(uint2*)(void*)(Xp + (size_t)g * 8) = v;
}

// -------- W [E][K][N] fp32 -> WT [E][N][K] fp8 of 32*W (z: 0=W1,1=W2) --------
__global__ void k_transw(const float* __restrict__ W1, u8* __restrict__ W1T,
                         const float* __restrict__ W2, u8* __restrict__ W2T) {
    __shared__ u8 tile[64][65];
    const float* W  = blockIdx.z ? W2  : W1;
    u8*          WT = blockIdx.z ? W2T : W1T;
    int e  = blockIdx.y;
    int tn = blockIdx.x & 15;
    int tk = blockIdx.x >> 4;
    const float* Wp = W  + (size_t)e * 1024 * 1024;
    u8*         WTp = WT + (size_t)e * 1024 * 1024;
    int c = threadIdx.x & 63, r0 = threadIdx.x >> 6;
#pragma unroll
    for (int i = 0; i < 16; ++i) {
        int r = r0 + i * 4;
        tile[r][c] = f2fp8(32.0f * Wp[(size_t)(tk * 64 + r) * 1024 + tn * 64 + c]);
    }
    __syncthreads();
#pragma unroll
    for (int i = 0; i < 16; ++i) {
        int r = r0 + i * 4;
        WTp[(size_t)(tn * 64 + r) * 1024 + tk * 64 + c] = tile[c][r];
    }
}

// ---------------- MX-fp8 MFMA GEMM: relu(A * (32B)^T * 2^-5 + bias) ----------------
// BK=64, double-buffered LDS (2x8KB per matrix = 32KB total -> 4 blocks/CU),
// ONE barrier per K-iter: next tile's global_load_lds issue before current tile's
// ds_read+MFMA, so load latency overlaps compute instead of draining at the barrier.
// XCD swizzle: flat%8 = m-tile within group of 8 -> A-panel L2 reuse per XCD.
// LDS swizzle: 16B chunk c of row r holds global chunk c^(r&3) (2-way residual = free).
// FUSE=false: store fp8 C.  FUSE=true: fold layer3 dot + slope + global sum.
template <bool FUSE>
__global__ __launch_bounds__(256, 4)
void k_gemm(const u8* __restrict__ A, const u8* __restrict__ BT,
            const float* __restrict__ bias, u8* __restrict__ C,
            const int* __restrict__ meta, const float* __restrict__ W3,
            const float* __restrict__ slope, float* __restrict__ out) {
    __shared__ u8 As[2][128 * 64];
    __shared__ u8 Bs[2][128 * 64];
    const int* offs = meta + 128;

    // XCD-aware swizzle (grid = dim3(8, 264) -> flat 0..2111)
    const int flat = blockIdx.y * 8 + blockIdx.x;
    const int mt = (flat >> 6) * 8 + (flat & 7);   // m tile
    const int nt = (flat & 63) >> 3;               // n tile
    if (mt >= MTILES) return;
    const int m0 = mt * 128, n0 = nt * 128;
    int e = (m0 >= offs[1]) + (m0 >= offs[2]) + (m0 >= offs[3]);

    const int t = threadIdx.x;
    const int w = t >> 6, lane = t & 63;
    const int l31 = lane & 31, khalf = lane >> 5;
    const int wm = w & 1, wn = w >> 1;   // 2x2 waves, each 64x64

    const u8* Ag = A + (size_t)m0 * 1024;
    const u8* Bg = BT + (size_t)e * 1024 * 1024 + (size_t)n0 * 1024;

    // staging: per matrix 2 instrs; instr i covers row i*64 + (t>>2), chunk t&3
    const int srow   = t >> 2;                    // 0..63
    const int gchunk = (t & 3) ^ (srow & 3);      // swizzled global 16-B chunk

    f32x16 acc[2][2] = {};

    // prologue: stage K-tile 0 into buffer 0
#pragma unroll
    for (int i = 0; i < 2; ++i)
        __builtin_amdgcn_global_load_lds(
            (const void*)(Ag + (size_t)(i * 64 + srow) * 1024 + gchunk * 16),
            (void*)(As[0] + i * 4096 + w * 1024), 16, 0, 0);
#pragma unroll
    for (int i = 0; i < 2; ++i)
        __builtin_amdgcn_global_load_lds(
            (const void*)(Bg + (size_t)(i * 64 + srow) * 1024 + gchunk * 16),
            (void*)(Bs[0] + i * 4096 + w * 1024), 16, 0, 0);
    __syncthreads();

    for (int kt = 0; kt < 16; ++kt) {
        const int cur = kt & 1;
        if (kt < 15) {
            const int kb = (kt + 1) * 64;
            const int nxt = cur ^ 1;
#pragma unroll
            for (int i = 0; i < 2; ++i)
                __builtin_amdgcn_global_load_lds(
                    (const void*)(Ag + (size_t)(i * 64 + srow) * 1024 + kb + gchunk * 16),
                    (void*)(As[nxt] + i * 4096 + w * 1024), 16, 0, 0);
#pragma unroll
            for (int i = 0; i < 2; ++i)
                __builtin_amdgcn_global_load_lds(
                    (const void*)(Bg + (size_t)(i * 64 + srow) * 1024 + kb + gchunk * 16),
                    (void*)(Bs[nxt] + i * 4096 + w * 1024), 16, 0, 0);
        }

        const int c0 = 2 * khalf;                 // even global chunk base (32B)
        i32x8 a[2], b[2];
#pragma unroll
        for (int mi = 0; mi < 2; ++mi) {
            int m = wm * 64 + mi * 32 + l31;
            const u8* base = As[cur] + m * 64;
            int lo = ((c0 ^ (m & 3)) << 4);
            uint4 q0 = *(const uint4*)(const void*)(base + lo);
            uint4 q1 = *(const uint4*)(const void*)(base + (lo ^ 16));
            union { uint4 q[2]; i32x8 v; } u;
            u.q[0] = q0; u.q[1] = q1;
            a[mi] = u.v;
        }
#pragma unroll
        for (int ni = 0; ni < 2; ++ni) {
            int n = wn * 64 + ni * 32 + l31;
            const u8* base = Bs[cur] + n * 64;
            int lo = ((c0 ^ (n & 3)) << 4);
            uint4 q0 = *(const uint4*)(const void*)(base + lo);
            uint4 q1 = *(const uint4*)(const void*)(base + (lo ^ 16));
            union { uint4 q[2]; i32x8 v; } u;
            u.q[0] = q0; u.q[1] = q1;
            b[ni] = u.v;
        }
#pragma unroll
        for (int mi = 0; mi < 2; ++mi)
#pragma unroll
            for (int ni = 0; ni < 2; ++ni)
                acc[mi][ni] = __builtin_amdgcn_mfma_scale_f32_32x32x64_f8f6f4(
                    a[mi], b[ni], acc[mi][ni],
                    0, 0,                       // cbsz=fp8(e4m3), blgp=fp8(e4m3)
                    0, 0x7F7F7F7F,              // A scale 2^0
                    0, 0x7A7A7A7A);             // B scale 2^-5 (undo 32*W)
        __syncthreads();   // also drains next-tile loads (they flew over ds+MFMA)
    }

    // epilogue.  32x32 C/D layout: col=lane&31, row=(reg&3)+8*(reg>>2)+4*(lane>>5)
    if (!FUSE) {
#pragma unroll
        for (int ni = 0; ni < 2; ++ni) {
            int col = n0 + wn * 64 + ni * 32 + l31;
            float bv = bias[e * 1024 + col];
#pragma unroll
            for (int mi = 0; mi < 2; ++mi) {
                int rowb = m0 + wm * 64 + mi * 32 + 4 * khalf;
#pragma unroll
                for (int reg = 0; reg < 16; ++reg) {
                    int rowg = rowb + (reg & 3) + 8 * (reg >> 2);
                    float v = acc[mi][ni][reg] + bv;
                    v = v > 0.f ? v : 0.f;
                    C[(size_t)rowg * 1024 + col] = f2fp8(v);
                }
            }
        }
    } else {
        const int segEnd = offs[e] + meta[e * 16];   // valid slots < segEnd
        const float se = slope[e];
        float psum = 0.f;
#pragma unroll
        for (int ni = 0; ni < 2; ++ni) {
            int col = n0 + wn * 64 + ni * 32 + l31;
            float bv  = bias[e * 1024 + col];
            float w3s = W3[e * 1024 + col] * se;
#pragma unroll
            for (int mi = 0; mi < 2; ++mi) {
                int rowb = m0 + wm * 64 + mi * 32 + 4 * khalf;
#pragma unroll
                for (int reg = 0; reg < 16; ++reg) {
                    int rowg = rowb + (reg & 3) + 8 * (reg >> 2);
                    float v = acc[mi][ni][reg] + bv;
                    v = v > 0.f ? v : 0.f;
                    psum += (rowg < segEnd) ? v * w3s : 0.f;
                }
            }
        }
#pragma unroll
        for (int o = 32; o; o >>= 1) psum += __shfl_xor(psum, o, 64);
        float* red = (float*)As[0];   // safe: all LDS reads done (loop-final barrier)
        if (lane == 0) red[w] = psum;
        __syncthreads();
        if (t == 0) atomicAdd(out, red[0] + red[1] + red[2] + red[3]);
    }
}

extern "C" void kernel_launch(void* const* d_in, const int* in_sizes, int n_in,
                              void* d_out, int out_size, void* d_ws, size_t ws_size,
                              hipStream_t stream) {
    const float* features = (const float*)d_in[0];
    const int*   sym      = (const int*)d_in[1];
    const float* W1       = (const float*)d_in[2];
    const float* b1       = (const float*)d_in[3];
    const float* W2       = (const float*)d_in[4];
    const float* b2       = (const float*)d_in[5];
    const float* W3       = (const float*)d_in[6];
    const float* b3       = (const float*)d_in[7];
    const float* slope    = (const float*)d_in[8];
    const float* inter    = (const float*)d_in[9];
    float* out = (float*)d_out;

    char* ws  = (char*)d_ws;
    u8*  Xp   = (u8*)(ws + XP_OFF);
    u8*  H1b  = (u8*)(ws + H1_OFF);
    u8*  W1T  = (u8*)(ws + W1T_OFF);
    u8*  W2T  = (u8*)(ws + W2T_OFF);
    int* perm = (int*)(ws + PERM_OFF);
    int* meta = (int*)(ws + META_OFF);

    k_count<<<NATOMS / 256, 256, 0, stream>>>(sym, meta);
    k_offsets<<<1, 256, 0, stream>>>(meta, slope, b3, inter, out);
    k_scatter<<<NATOMS / 256, 256, 0, stream>>>(sym, meta, perm);
    k_convx<<<(MCAP * 128) / 256, 256, 0, stream>>>(features, perm, meta, Xp);
    k_transw<<<dim3(256, 4, 2), 256, 0, stream>>>(W1, W1T, W2, W2T);
    k_gemm<false><<<dim3(8, 264), 256, 0, stream>>>(Xp, W1T, b1, H1b, meta,
                                                    nullptr, nullptr, nullptr);
    k_gemm<true><<<dim3(8, 264), 256, 0, stream>>>(H1b, W2T, b2, nullptr, meta,
                                                   W3, slope, out);
}

// Round 9
// 351.195 us; speedup vs baseline: 1.0666x; 1.0666x over previous
//
#include <hip/hip_runtime.h>
#include <hip/hip_bf16.h>
#include <stdint.h>

// Problem constants
#define NATOMS 32768
#define DDIM   1024
#define HDIM   1024
#define ENUM   4
#define MCAP   (NATOMS + ENUM * 128)   // 33280 = 260 * 128 (worst-case padded M)
#define MTILES 260

typedef unsigned short u16;
typedef unsigned char  u8;
typedef __attribute__((ext_vector_type(8)))  int   i32x8;
typedef __attribute__((ext_vector_type(16))) float f32x16;

// ---- workspace layout (bytes) ----
static const size_t XP_OFF   = 0;
static const size_t H1_OFF   = XP_OFF  + (size_t)MCAP * 1024;
static const size_t W1T_OFF  = H1_OFF  + (size_t)MCAP * 1024;
static const size_t W2T_OFF  = W1T_OFF + (size_t)ENUM * 1024 * 1024;
static const size_t PERM_OFF = W2T_OFF + (size_t)ENUM * 1024 * 1024;
static const size_t META_OFF = PERM_OFF + (size_t)MCAP * 4;
// meta ints: count[e] at e*16; cursor[e] at 64+e*16; offs[0..3] at 128..131;
// Mpad at 132; per-block count partials at 256 + b*4 + e  (b in [0,128))

__device__ __forceinline__ u8 f2fp8(float x) {
    int w = __builtin_amdgcn_cvt_pk_fp8_f32(x, x, 0, false);
    return (u8)(w & 0xFF);
}

// ------- count atoms per expert: per-block partials, no pre-zeroed meta -------
__global__ void k_count(const int* __restrict__ sym, int* __restrict__ meta) {
    __shared__ int cnt[4];
    int t = threadIdx.x;
    if (t < 4) cnt[t] = 0;
    __syncthreads();
    int n = blockIdx.x * 256 + t;
    int lane = t & 63;
    int e = sym[n];
#pragma unroll
    for (int j = 0; j < ENUM; ++j) {
        unsigned long long mask = __ballot(e == j);
        if (mask) {
            int leader = __ffsll((long long)mask) - 1;
            if (lane == leader) atomicAdd(&cnt[j], __popcll(mask));
        }
    }
    __syncthreads();
    if (t < 4) meta[256 + blockIdx.x * 4 + t] = cnt[t];
}

// -- sum partials; write counts/cursors/offs/Mpad; out = constant energy term --
__global__ void k_offsets(int* __restrict__ meta, const float* __restrict__ slope,
                          const float* __restrict__ b3, const float* __restrict__ inter,
                          float* __restrict__ out) {
    __shared__ int tot[4];
    int t = threadIdx.x;
    if (t < 4) {
        int s = 0;
#pragma unroll 8
        for (int b = 0; b < 128; ++b) s += meta[256 + b * 4 + t];
        tot[t] = s;
    }
    __syncthreads();
    if (t == 0) {
        int off = 0;
        float c = 0.f;
        for (int e = 0; e < 4; ++e) {
            int cnt = tot[e];
            meta[e * 16]     = cnt;   // total count
            meta[128 + e]    = off;   // segment start
            meta[64 + e*16]  = off;   // scatter cursor
            c += (float)cnt * (slope[e] * b3[e] + inter[e]);
            off += (cnt + 127) & ~127;
        }
        meta[132] = off;              // Mpad
        out[0] = c;                   // per-atom constant terms, summed
    }
}

// ---------------- scatter atom ids (wave-aggregated: 4 atomics/wave) ----------------
__global__ void k_scatter(const int* __restrict__ sym, int* __restrict__ meta,
                          int* __restrict__ perm) {
    int n = blockIdx.x * 256 + threadIdx.x;
    int lane = threadIdx.x & 63;
    int e = sym[n];
#pragma unroll
    for (int j = 0; j < ENUM; ++j) {
        unsigned long long mask = __ballot(e == j);
        if (mask) {
            int leader = __ffsll((long long)mask) - 1;
            int base = 0;
            if (lane == leader)
                base = atomicAdd(&meta[64 + j * 16], __popcll(mask));
            base = __shfl(base, leader, 64);
            if (e == j) {
                int rank = __popcll(mask & ((1ull << lane) - 1ull));
                perm[base + rank] = n;
            }
        }
    }
}

// -------- features fp32 -> permuted fp8 (pad slots -> zeros, via offs/count) --------
__global__ void k_convx(const float* __restrict__ F, const int* __restrict__ perm,
                        const int* __restrict__ meta, u8* __restrict__ Xp) {
    int g = blockIdx.x * 256 + threadIdx.x;    // chunk of 8 elements
    int slot = g >> 7, c = g & 127;
    const int* offs = meta + 128;
    int e = (slot >= offs[1]) + (slot >= offs[2]) + (slot >= offs[3]);
    bool valid = slot < offs[e] + meta[e * 16];
    uint2 v;
    if (!valid) {
        v.x = 0u; v.y = 0u;
    } else {
        int src = perm[slot];
        const float* fp = F + (size_t)src * 1024 + c * 8;
        int w0 = 0, w1 = 0;
        w0 = __builtin_amdgcn_cvt_pk_fp8_f32(fp[0], fp[1], w0, false);
        w0 = __builtin_amdgcn_cvt_pk_fp8_f32(fp[2], fp[3], w0, true);
        w1 = __builtin_amdgcn_cvt_pk_fp8_f32(fp[4], fp[5], w1, false);
        w1 = __builtin_amdgcn_cvt_pk_fp8_f32(fp[6], fp[7], w1, true);
        v.x = (unsigned)w0; v.y = (unsigned)w1;
    }
    *(uint2*)(void*)(Xp + (size_t)g * 8) = v;
}

// -------- W [E][K][N] fp32 -> WT [E][N][K] fp8 of 32*W (z: 0=W1,1=W2) --------
__global__ void k_transw(const float* __restrict__ W1, u8* __restrict__ W1T,
                         const float* __restrict__ W2, u8* __restrict__ W2T) {
    __shared__ u8 tile[64][65];
    const float* W  = blockIdx.z ? W2  : W1;
    u8*          WT = blockIdx.z ? W2T : W1T;
    int e  = blockIdx.y;
    int tn = blockIdx.x & 15;
    int tk = blockIdx.x >> 4;
    const float* Wp = W  + (size_t)e * 1024 * 1024;
    u8*         WTp = WT + (size_t)e * 1024 * 1024;
    int c = threadIdx.x & 63, r0 = threadIdx.x >> 6;
#pragma unroll
    for (int i = 0; i < 16; ++i) {
        int r = r0 + i * 4;
        tile[r][c] = f2fp8(32.0f * Wp[(size_t)(tk * 64 + r) * 1024 + tn * 64 + c]);
    }
    __syncthreads();
#pragma unroll
    for (int i = 0; i < 16; ++i) {
        int r = r0 + i * 4;
        WTp[(size_t)(tn * 64 + r) * 1024 + tk * 64 + c] = tile[c][r];
    }
}

// ---------------- MX-fp8 MFMA GEMM: relu(A * (32B)^T * 2^-5 + bias) ----------------
// R7 structure (best measured): BK=128, single-buffered 32 KB LDS -> 4 blocks/CU.
// R8's explicit double-buffer REGRESSED (356->375 us): the per-iter barrier still
// drains vmcnt(0), so prefetch bought nothing and added addressing overhead
// (matches learn_hip m99/m100/m131-141 on the m97 structure).
// XCD swizzle: flat%8 = m-tile within group of 8 -> A-panel L2 reuse per XCD.
// LDS swizzle: 16B chunk c of row r holds global chunk c^(r&7) -> conflict-free.
// FUSE=false: store fp8 C.  FUSE=true: fold layer3 dot + slope + global sum.
template <bool FUSE>
__global__ __launch_bounds__(256, 4)
void k_gemm(const u8* __restrict__ A, const u8* __restrict__ BT,
            const float* __restrict__ bias, u8* __restrict__ C,
            const int* __restrict__ meta, const float* __restrict__ W3,
            const float* __restrict__ slope, float* __restrict__ out) {
    __shared__ u8 As[128 * 128];
    __shared__ u8 Bs[128 * 128];
    const int* offs = meta + 128;

    // XCD-aware swizzle (grid = dim3(8, 264) -> flat 0..2111)
    const int flat = blockIdx.y * 8 + blockIdx.x;
    const int mt = (flat >> 6) * 8 + (flat & 7);   // m tile
    const int nt = (flat & 63) >> 3;               // n tile
    if (mt >= MTILES) return;
    const int m0 = mt * 128, n0 = nt * 128;
    int e = (m0 >= offs[1]) + (m0 >= offs[2]) + (m0 >= offs[3]);

    const int t = threadIdx.x;
    const int w = t >> 6, lane = t & 63;
    const int l31 = lane & 31, khalf = lane >> 5;
    const int wm = w & 1, wn = w >> 1;   // 2x2 waves, each 64x64

    const u8* Ag = A + (size_t)m0 * 1024;
    const u8* Bg = BT + (size_t)e * 1024 * 1024 + (size_t)n0 * 1024;

    // staging: per matrix 4 instrs; instr i covers rows i*32+(t>>3), chunk t&7
    const int srow   = t >> 3;                    // 0..31
    const int gchunk = (t & 7) ^ (srow & 7);      // swizzled global 16-B chunk

    f32x16 acc[2][2] = {};

    for (int kt = 0; kt < 1024 / 128; ++kt) {
        const int kb = kt * 128;
#pragma unroll
        for (int i = 0; i < 4; ++i) {
            int row = i * 32 + srow;
            __builtin_amdgcn_global_load_lds(
                (const void*)(Ag + (size_t)row * 1024 + kb + gchunk * 16),
                (void*)(As + i * 4096 + w * 1024), 16, 0, 0);
        }
#pragma unroll
        for (int i = 0; i < 4; ++i) {
            int row = i * 32 + srow;
            __builtin_amdgcn_global_load_lds(
                (const void*)(Bg + (size_t)row * 1024 + kb + gchunk * 16),
                (void*)(Bs + i * 4096 + w * 1024), 16, 0, 0);
        }
        __syncthreads();

#pragma unroll
        for (int kk = 0; kk < 2; ++kk) {
            const int c0 = 4 * kk + 2 * khalf;    // even
            i32x8 a[2], b[2];
#pragma unroll
            for (int mi = 0; mi < 2; ++mi) {
                int m = wm * 64 + mi * 32 + l31;
                const u8* base = As + m * 128;
                int lo = ((c0 ^ (m & 7)) << 4);
                uint4 q0 = *(const uint4*)(const void*)(base + lo);
                uint4 q1 = *(const uint4*)(const void*)(base + (lo ^ 16));
                union { uint4 q[2]; i32x8 v; } u;
                u.q[0] = q0; u.q[1] = q1;
                a[mi] = u.v;
            }
#pragma unroll
            for (int ni = 0; ni < 2; ++ni) {
                int n = wn * 64 + ni * 32 + l31;
                const u8* base = Bs + n * 128;
                int lo = ((c0 ^ (n & 7)) << 4);
                uint4 q0 = *(const uint4*)(const void*)(base + lo);
                uint4 q1 = *(const uint4*)(const void*)(base + (lo ^ 16));
                union { uint4 q[2]; i32x8 v; } u;
                u.q[0] = q0; u.q[1] = q1;
                b[ni] = u.v;
            }
#pragma unroll
            for (int mi = 0; mi < 2; ++mi)
#pragma unroll
                for (int ni = 0; ni < 2; ++ni)
                    acc[mi][ni] = __builtin_amdgcn_mfma_scale_f32_32x32x64_f8f6f4(
                        a[mi], b[ni], acc[mi][ni],
                        0, 0,                       // cbsz=fp8(e4m3), blgp=fp8(e4m3)
                        0, 0x7F7F7F7F,              // A scale 2^0
                        0, 0x7A7A7A7A);             // B scale 2^-5 (undo 32*W)
        }
        __syncthreads();
    }

    // epilogue.  32x32 C/D layout: col=lane&31, row=(reg&3)+8*(reg>>2)+4*(lane>>5)
    if (!FUSE) {
#pragma unroll
        for (int ni = 0; ni < 2; ++ni) {
            int col = n0 + wn * 64 + ni * 32 + l31;
            float bv = bias[e * 1024 + col];
#pragma unroll
            for (int mi = 0; mi < 2; ++mi) {
                int rowb = m0 + wm * 64 + mi * 32 + 4 * khalf;
#pragma unroll
                for (int reg = 0; reg < 16; ++reg) {
                    int rowg = rowb + (reg & 3) + 8 * (reg >> 2);
                    float v = acc[mi][ni][reg] + bv;
                    v = v > 0.f ? v : 0.f;
                    C[(size_t)rowg * 1024 + col] = f2fp8(v);
                }
            }
        }
    } else {
        const int segEnd = offs[e] + meta[e * 16];   // valid slots < segEnd
        const float se = slope[e];
        float psum = 0.f;
#pragma unroll
        for (int ni = 0; ni < 2; ++ni) {
            int col = n0 + wn * 64 + ni * 32 + l31;
            float bv  = bias[e * 1024 + col];
            float w3s = W3[e * 1024 + col] * se;
#pragma unroll
            for (int mi = 0; mi < 2; ++mi) {
                int rowb = m0 + wm * 64 + mi * 32 + 4 * khalf;
#pragma unroll
                for (int reg = 0; reg < 16; ++reg) {
                    int rowg = rowb + (reg & 3) + 8 * (reg >> 2);
                    float v = acc[mi][ni][reg] + bv;
                    v = v > 0.f ? v : 0.f;
                    psum += (rowg < segEnd) ? v * w3s : 0.f;
                }
            }
        }
#pragma unroll
        for (int o = 32; o; o >>= 1) psum += __shfl_xor(psum, o, 64);
        float* red = (float*)As;    // safe: all LDS reads done (loop-final barrier)
        if (lane == 0) red[w] = psum;
        __syncthreads();
        if (t == 0) atomicAdd(out, red[0] + red[1] + red[2] + red[3]);
    }
}

extern "C" void kernel_launch(void* const* d_in, const int* in_sizes, int n_in,
                              void* d_out, int out_size, void* d_ws, size_t ws_size,
                              hipStream_t stream) {
    const float* features = (const float*)d_in[0];
    const int*   sym      = (const int*)d_in[1];
    const float* W1       = (const float*)d_in[2];
    const float* b1       = (const float*)d_in[3];
    const float* W2       = (const float*)d_in[4];
    const float* b2       = (const float*)d_in[5];
    const float* W3       = (const float*)d_in[6];
    const float* b3       = (const float*)d_in[7];
    const float* slope    = (const float*)d_in[8];
    const float* inter    = (const float*)d_in[9];
    float* out = (float*)d_out;

    char* ws  = (char*)d_ws;
    u8*  Xp   = (u8*)(ws + XP_OFF);
    u8*  H1b  = (u8*)(ws + H1_OFF);
    u8*  W1T  = (u8*)(ws + W1T_OFF);
    u8*  W2T  = (u8*)(ws + W2T_OFF);
    int* perm = (int*)(ws + PERM_OFF);
    int* meta = (int*)(ws + META_OFF);

    k_count<<<NATOMS / 256, 256, 0, stream>>>(sym, meta);
    k_offsets<<<1, 256, 0, stream>>>(meta, slope, b3, inter, out);
    k_scatter<<<NATOMS / 256, 256, 0, stream>>>(sym, meta, perm);
    k_convx<<<(MCAP * 128) / 256, 256, 0, stream>>>(features, perm, meta, Xp);
    k_transw<<<dim3(256, 4, 2), 256, 0, stream>>>(W1, W1T, W2, W2T);
    k_gemm<false><<<dim3(8, 264), 256, 0, stream>>>(Xp, W1T, b1, H1b, meta,
                                                    nullptr, nullptr, nullptr);
    k_gemm<true><<<dim3(8, 264), 256, 0, stream>>>(H1b, W2T, b2, nullptr, meta,
                                                   W3, slope, out);
}